// Round 10
// baseline (344.648 us; speedup 1.0000x reference)
//
#include <hip/hip_runtime.h>

#define NB 32
#define NR 16384
#define NF 256
#define NH 16
#define TOT (NB*NR)
#define RPB 256      // rows per block in k_scores
#define KC 32        // K-chunk
#define LSTR 33      // LDS row stride

typedef unsigned long long u64;

__device__ __forceinline__ unsigned int f2u(float f) {
    unsigned int u = __float_as_uint(f);
    return (u & 0x80000000u) ? ~u : (u | 0x80000000u);
}
__device__ __forceinline__ float u2f(unsigned int s) {
    unsigned int u = (s & 0x80000000u) ? (s ^ 0x80000000u) : ~s;
    return __uint_as_float(u);
}

// ---------------- Kernel 0: fold constants + init mnmx/done ---------------
__global__ __launch_bounds__(256) void k_prep(
    const float* __restrict__ ln1_g, const float* __restrict__ ln1_b,
    const float* __restrict__ W1, const float* __restrict__ b1,
    const float* __restrict__ ln2_g, const float* __restrict__ ln2_b,
    const float* __restrict__ W2, const float* __restrict__ b2,
    float* __restrict__ W1g, float* __restrict__ consts,
    unsigned* __restrict__ mnmx, unsigned* __restrict__ done)
{
    __shared__ float redc[16][16];
    __shared__ float redu[16][16];
    const int t = threadIdx.x;
    for (int e = t; e < NF*NH; e += 256) {
        int k = e >> 4;
        W1g[e] = ln1_g[k] * W1[e];
    }
    if (t < NB) { mnmx[2*t] = 0u; mnmx[2*t + 1] = 0xFFFFFFFFu; done[t] = 0u; }
    const int h = t & 15, kp = t >> 4;
    float pc = 0.f, pu = 0.f;
    #pragma unroll
    for (int r = 0; r < 16; ++r) {
        int k = kp*16 + r;
        float w = W1[k*NH + h];
        pc += ln1_b[k] * w;
        pu += ln1_g[k] * w;
    }
    redc[kp][h] = pc; redu[kp][h] = pu;
    __syncthreads();
    if (t < 16) {
        float sc = 0.f, su = 0.f;
        #pragma unroll
        for (int r = 0; r < 16; ++r) { sc += redc[r][t]; su += redu[r][t]; }
        consts[t]      = sc + b1[t];
        consts[16 + t] = su;
        consts[32 + t] = ln2_g[t] * W2[t];
    }
    if (t == 0) {
        float U2 = 0.f, C2 = b2[0];
        for (int hh = 0; hh < 16; ++hh) {
            U2 += ln2_g[hh] * W2[hh];
            C2 += ln2_b[hh] * W2[hh];
        }
        consts[48] = U2;
        consts[49] = C2;
    }
}

// ---------------- Kernel 1: thread-per-row fused scores + batch min/max ---
__global__ __launch_bounds__(256) void k_scores(
    const float* __restrict__ table,
    const float* __restrict__ W1g,
    const float* __restrict__ consts,
    u64* __restrict__ keys, unsigned* __restrict__ mnmx)
{
    __shared__ float xt[RPB * LSTR];   // 33,792 B
    __shared__ unsigned redmx[4], redmn[4];
    const int t = threadIdx.x;
    const size_t rowBase = (size_t)blockIdx.x * RPB;
    const int bb = blockIdx.x >> 6;    // batch (64 blocks per batch)
    const float4* __restrict__ Wg4 = (const float4*)W1g;

    float dx[16];
    #pragma unroll
    for (int h = 0; h < 16; ++h) dx[h] = 0.f;
    float sum = 0.f, ssq = 0.f;

    for (int c = 0; c < NF/KC; ++c) {
        float4 v[8];
        #pragma unroll
        for (int p = 0; p < 8; ++p) {
            int q = p*256 + t;
            int r = q >> 3, cg = q & 7;
            v[p] = *(const float4*)(table + (rowBase + r)*NF + c*KC + cg*4);
        }
        __syncthreads();
        #pragma unroll
        for (int p = 0; p < 8; ++p) {
            int q = p*256 + t;
            int r = q >> 3, cg = q & 7;
            float* dst = xt + r*LSTR + cg*4;
            dst[0] = v[p].x; dst[1] = v[p].y; dst[2] = v[p].z; dst[3] = v[p].w;
        }
        __syncthreads();

        const float* __restrict__ xr = xt + t*LSTR;
        #pragma unroll 4
        for (int k = 0; k < KC; ++k) {
            const int kk = c*KC + k;
            float x = xr[k];
            float4 w0 = Wg4[kk*4+0];
            float4 w1 = Wg4[kk*4+1];
            float4 w2 = Wg4[kk*4+2];
            float4 w3 = Wg4[kk*4+3];
            sum += x;
            ssq = fmaf(x, x, ssq);
            dx[ 0] = fmaf(x, w0.x, dx[ 0]);
            dx[ 1] = fmaf(x, w0.y, dx[ 1]);
            dx[ 2] = fmaf(x, w0.z, dx[ 2]);
            dx[ 3] = fmaf(x, w0.w, dx[ 3]);
            dx[ 4] = fmaf(x, w1.x, dx[ 4]);
            dx[ 5] = fmaf(x, w1.y, dx[ 5]);
            dx[ 6] = fmaf(x, w1.z, dx[ 6]);
            dx[ 7] = fmaf(x, w1.w, dx[ 7]);
            dx[ 8] = fmaf(x, w2.x, dx[ 8]);
            dx[ 9] = fmaf(x, w2.y, dx[ 9]);
            dx[10] = fmaf(x, w2.z, dx[10]);
            dx[11] = fmaf(x, w2.w, dx[11]);
            dx[12] = fmaf(x, w3.x, dx[12]);
            dx[13] = fmaf(x, w3.y, dx[13]);
            dx[14] = fmaf(x, w3.z, dx[14]);
            dx[15] = fmaf(x, w3.w, dx[15]);
        }
    }

    const float mu   = sum * (1.f/NF);
    const float var  = ssq * (1.f/NF) - mu*mu;
    const float rstd = rsqrtf(var + 1e-5f);
    float s2 = 0.f, q2 = 0.f, dh = 0.f;
    #pragma unroll
    for (int h = 0; h < 16; ++h) {
        float hv = rstd * (dx[h] - mu * consts[16 + h]) + consts[h];
        hv = fmaxf(hv, 0.f);
        s2 += hv;
        q2 = fmaf(hv, hv, q2);
        dh = fmaf(hv, consts[32 + h], dh);
    }
    const float mu2   = s2 * (1.f/NH);
    const float var2  = q2 * (1.f/NH) - mu2*mu2;
    const float rstd2 = rsqrtf(var2 + 1e-5f);
    const float sc    = rstd2 * (dh - mu2 * consts[48]) + consts[49];

    const size_t row = rowBase + t;
    const unsigned k32 = f2u(sc);
    keys[row] = ((u64)k32 << 32) | (u64)(row & (NR-1));

    unsigned wmx = k32, wmn = k32;
    #pragma unroll
    for (int m = 32; m >= 1; m >>= 1) {
        wmx = max(wmx, (unsigned)__shfl_xor((int)wmx, m, 64));
        wmn = min(wmn, (unsigned)__shfl_xor((int)wmn, m, 64));
    }
    const int lane = t & 63, wid = t >> 6;
    if (lane == 0) { redmx[wid] = wmx; redmn[wid] = wmn; }
    __syncthreads();
    if (t == 0) {
        unsigned bx = redmx[0], bn = redmn[0];
        #pragma unroll
        for (int w = 1; w < 4; ++w) { bx = max(bx, redmx[w]); bn = min(bn, redmn[w]); }
        atomicMax(&mnmx[2*bb], bx);
        atomicMin(&mnmx[2*bb + 1], bn);
    }
}

// ---------------- Kernel 2a: full bitonic sort of 4096-chunks -------------
__global__ __launch_bounds__(1024) void k_sort_local(u64* __restrict__ keys) {
    __shared__ u64 sk[4096];
    const int base_g = blockIdx.x * 4096;
    const int tid = threadIdx.x;
    #pragma unroll
    for (int it = 0; it < 4; ++it) sk[tid + it*1024] = keys[base_g + tid + it*1024];
    __syncthreads();
    for (int k = 2; k <= 4096; k <<= 1) {
        for (int j = k >> 1; j > 0; j >>= 1) {
            int ii[2]; u64 a[2], c[2];
            #pragma unroll
            for (int it = 0; it < 2; ++it) {
                int q = tid + it*1024;
                int i = ((q & ~(j-1)) << 1) | (q & (j-1));
                ii[it] = i;
                a[it] = sk[i]; c[it] = sk[i | j];
            }
            #pragma unroll
            for (int it = 0; it < 2; ++it) {
                int gi = (base_g + ii[it]) & (NR - 1);
                bool dir = ((gi & k) == 0);
                if ((c[it] > a[it]) == dir) { sk[ii[it]] = c[it]; sk[ii[it] | j] = a[it]; }
            }
            __syncthreads();
        }
    }
    #pragma unroll
    for (int it = 0; it < 4; ++it) keys[base_g + tid + it*1024] = sk[tid + it*1024];
}

// ---------------- Kernel 2b: stage k=8192 complete on 8192-chunks ---------
__global__ __launch_bounds__(1024) void k_mid8(u64* __restrict__ keys) {
    __shared__ u64 sk[8192];   // 64 KiB
    const int base_g = blockIdx.x * 8192;
    const int tid = threadIdx.x;
    #pragma unroll
    for (int it = 0; it < 8; ++it) sk[tid + it*1024] = keys[base_g + tid + it*1024];
    const bool dir = (((base_g & (NR-1)) & 8192) == 0);
    __syncthreads();
    for (int j = 4096; j >= 1; j >>= 1) {
        int ii[4]; u64 a[4], c[4];
        #pragma unroll
        for (int it = 0; it < 4; ++it) {
            int q = tid + it*1024;
            int i = ((q & ~(j-1)) << 1) | (q & (j-1));
            ii[it] = i;
            a[it] = sk[i]; c[it] = sk[i | j];
        }
        #pragma unroll
        for (int it = 0; it < 4; ++it) {
            if ((c[it] > a[it]) == dir) { sk[ii[it]] = c[it]; sk[ii[it] | j] = a[it]; }
        }
        __syncthreads();
    }
    #pragma unroll
    for (int it = 0; it < 8; ++it) keys[base_g + tid + it*1024] = sk[tid + it*1024];
}

// ---------------- Kernel 2c: stage k=16384 phases j=8192,4096 (registers) -
__global__ __launch_bounds__(256) void k_cross16(u64* __restrict__ keys) {
    const int gt = blockIdx.x * 256 + threadIdx.x;   // TOT/4 threads
    const int b = gt >> 12;
    const int c = gt & 4095;
    u64* kb = keys + (size_t)b * NR + c;
    u64 e0 = kb[0], e1 = kb[4096], e2 = kb[8192], e3 = kb[12288];
    u64 t;
    // j=8192 (descending)
    if (e2 > e0) { t = e0; e0 = e2; e2 = t; }
    if (e3 > e1) { t = e1; e1 = e3; e3 = t; }
    // j=4096
    if (e1 > e0) { t = e0; e0 = e1; e1 = t; }
    if (e3 > e2) { t = e2; e2 = e3; e3 = t; }
    kb[0] = e0; kb[4096] = e1; kb[8192] = e2; kb[12288] = e3;
}

// ---------------- Kernel 3: tail + chunk hull + (last block) merge + out --
__global__ __launch_bounds__(1024) void k_hullAB(
    u64* __restrict__ keys, const unsigned* __restrict__ mnmx,
    const int* __restrict__ capp,
    int* __restrict__ Hg, double* __restrict__ Svg,
    int* __restrict__ cntg, double* __restrict__ sumg,
    unsigned* __restrict__ done,
    float* __restrict__ out_soft, float* __restrict__ out_bins)
{
    __shared__ __align__(16) char smem[32768 + 16384 + 128 + 1024 + 3*512];
    u64*    sk  = (u64*)smem;            // [4096] sort phase
    double* S   = (double*)smem;         // [4096] scan phase (overlay)
    int*    H   = (int*)(smem + 32768);  // [4096]
    double* Wt  = (double*)(smem + 32768 + 16384);
    int*    cnt = (int*)(smem + 32768 + 16384 + 128);
    int*    ti  = (int*)(smem + 32768 + 16384 + 128 + 1024);
    int*    tj  = (int*)(smem + 32768 + 16384 + 128 + 1024 + 512);
    int*    crA = (int*)(smem + 32768 + 16384 + 128 + 1024 + 1024);
    __shared__ double beta[5];
    __shared__ int cntB[4];
    __shared__ int tiS[2], tjS[2], crS[2];
    __shared__ int amLast;

    const int blk = blockIdx.x;
    const int b = blk >> 2, c = blk & 3;
    const int tid = threadIdx.x, lane = tid & 63, wid = tid >> 6;
    u64* kg = keys + (size_t)b * NR + c * 4096;

    // ---- final bitonic tail (k=16384, j<=2048, descending) ----
    #pragma unroll
    for (int it = 0; it < 4; ++it) sk[tid + it*1024] = kg[tid + it*1024];
    __syncthreads();
    for (int j = 2048; j >= 1; j >>= 1) {
        int ii[2]; u64 a[2], cc[2];
        #pragma unroll
        for (int it = 0; it < 2; ++it) {
            int q = tid + it*1024;
            int i = ((q & ~(j-1)) << 1) | (q & (j-1));
            ii[it] = i;
            a[it] = sk[i]; cc[it] = sk[i | j];
        }
        #pragma unroll
        for (int it = 0; it < 2; ++it) {
            if (cc[it] > a[it]) { sk[ii[it]] = cc[it]; sk[ii[it] | j] = a[it]; }
        }
        __syncthreads();
    }

    // ---- writeback + local f64 scan of this chunk ----
    const float mx = u2f(mnmx[2*b]);
    const float mn = u2f(mnmx[2*b + 1]);
    const float scale = 10000.0f / (mx - mn);
    const int gofs = c * 4096;
    const int b4 = tid * 4;

    u64 kv[4];
    #pragma unroll
    for (int r = 0; r < 4; ++r) kv[r] = sk[b4 + r];
    #pragma unroll
    for (int it = 0; it < 4; ++it) kg[tid + it*1024] = sk[tid + it*1024];

    double loc[4];
    double acc = 0.0;
    #pragma unroll
    for (int r = 0; r < 4; ++r) {
        int ig = gofs + b4 + r;
        float s_i = (u2f((unsigned)(kv[r] >> 32)) - mn) * scale;
        acc += (double)s_i - (double)(NR - ig);
        loc[r] = acc;
    }
    __syncthreads();     // all sk reads done before S overlay

    double v = acc;
    #pragma unroll
    for (int d = 1; d < 64; d <<= 1) {
        double o = __shfl_up(v, d, 64);
        if (lane >= d) v += o;
    }
    if (lane == 63) Wt[wid] = v;
    __syncthreads();
    if (tid < 16) {
        double w = Wt[tid];
        #pragma unroll
        for (int d = 1; d < 16; d <<= 1) {
            double o = __shfl_up(w, d, 16);
            if ((tid & 15) >= d) w += o;
        }
        Wt[tid] = w;
    }
    __syncthreads();
    const double wbase = (wid == 0) ? 0.0 : Wt[wid - 1];
    const double excl = wbase + (v - acc);
    #pragma unroll
    for (int r = 0; r < 4; ++r) S[b4 + r] = excl + loc[r];
    __syncthreads();
    if (tid == 0) sumg[blk] = S[4095];

    #define SVA(k) ((k) == 0 ? 0.0 : S[(k)-1])

    // ---- level-0: 16-point hulls on threads 0..255 ----
    if (tid < 256) {
        const int base16 = tid * 16;
        int out = 0;
        int k1 = 0, k2 = 0; double y1 = 0.0, y2 = 0.0;
        #pragma unroll 1
        for (int r = 0; r < 16; ++r) {
            int k = base16 + r;
            double yk = SVA(k);
            while (out >= 2) {
                double cr_ = (double)(k1 - k2)*(yk - y2) - (y1 - y2)*(double)(k - k2);
                if (cr_ >= 0.0) {
                    --out; k1 = k2; y1 = y2;
                    if (out >= 2) { k2 = H[base16 + out - 2]; y2 = SVA(k2); }
                } else break;
            }
            H[base16 + out] = k;
            k2 = k1; y2 = y1; k1 = k; y1 = yk;
            ++out;
        }
        cnt[tid] = out;
    }

    // ---- 8 merge levels (256 -> 1) ----
    for (int lev = 0; lev < 8; ++lev) {
        __syncthreads();
        const int pairs = 128 >> lev;
        const int Wd = 16 << lev;
        if (tid < pairs) {
            const int lbase = tid * 2 * Wd;
            const int rbase = lbase + Wd;
            int cl = cnt[(2*tid) << lev];
            int cr = cnt[(2*tid+1) << lev];
            int i = cl - 1, j = 0;
            int kLi = H[lbase + i];            double yLi = SVA(kLi);
            int kLm = 0;                       double yLm = 0.0;
            if (i > 0) { kLm = H[lbase + i - 1]; yLm = SVA(kLm); }
            int kRj = H[rbase];                double yRj = SVA(kRj);
            int kRn = 0;                       double yRn = 0.0;
            if (cr > 1) { kRn = H[rbase + 1]; yRn = SVA(kRn); }
            bool moved = true;
            while (moved) {
                moved = false;
                while (i > 0) {
                    double cr_ = (double)(kLi - kLm)*(yRj - yLm)
                               - (yLi - yLm)*(double)(kRj - kLm);
                    if (cr_ >= 0.0) {
                        --i; kLi = kLm; yLi = yLm;
                        if (i > 0) { kLm = H[lbase + i - 1]; yLm = SVA(kLm); }
                        moved = true;
                    } else break;
                }
                while (j < cr - 1) {
                    double cr_ = (double)(kRj - kLi)*(yRn - yLi)
                               - (yRj - yLi)*(double)(kRn - kLi);
                    if (cr_ >= 0.0) {
                        ++j; kRj = kRn; yRj = yRn;
                        if (j < cr - 1) { kRn = H[rbase + j + 1]; yRn = SVA(kRn); }
                        moved = true;
                    } else break;
                }
            }
            ti[tid] = i; tj[tid] = j; crA[tid] = cr;
            cnt[(2*tid) << lev] = (i + 1) + (cr - j);
        }
        __syncthreads();
        const int tpp = 8 << lev;
        const int p = tid / tpp;
        const int q = tid % tpp;
        int vals[8];
        int len = 0, srcb = 0, dstb = 0;
        if (p < pairs) {
            const int lbase = p * 2 * Wd;
            const int rbase = lbase + Wd;
            const int i = ti[p], j = tj[p], cr = crA[p];
            len = cr - j;
            srcb = rbase + j;
            dstb = lbase + i + 1;
            #pragma unroll
            for (int t2 = 0; t2 < 8; ++t2) {
                int e2 = q + t2 * tpp;
                if (e2 < len) vals[t2] = H[srcb + e2];
            }
        }
        __syncthreads();
        if (p < pairs) {
            #pragma unroll
            for (int t2 = 0; t2 < 8; ++t2) {
                int e2 = q + t2 * tpp;
                if (e2 < len) H[dstb + e2] = vals[t2];
            }
        }
        __syncthreads();
    }

    // ---- publish chunk hull ----
    const int m0 = cnt[0];
    for (int p = tid; p < m0; p += 1024) {
        int k = H[p];
        Hg[(size_t)blk * 4096 + p]  = k + gofs;
        Svg[(size_t)blk * 4096 + p] = SVA(k);
    }
    if (tid == 0) cntg[blk] = m0;
    #undef SVA
    __syncthreads();

    // ---- last-block-done: merge + outputs ----
    if (tid == 0) {
        __threadfence();
        unsigned old = atomicAdd(&done[b], 1u);
        amLast = (old == 3u);
    }
    __syncthreads();
    if (!amLast) return;
    __threadfence();   // acquire: other chunks' Hg/Svg/cntg/sumg now visible

    int*    Hb = Hg  + (size_t)b * NR;
    double* Sb = Svg + (size_t)b * NR;

    if (tid < 4) cntB[tid] = cntg[4*b + tid];
    if (tid == 0) {
        double s = 0.0;
        #pragma unroll
        for (int cc = 0; cc < 4; ++cc) { beta[cc] = s; s += sumg[4*b + cc]; }
        beta[4] = s;
    }
    __syncthreads();

    #pragma unroll 1
    for (int cc = 0; cc < 4; ++cc) {
        const double bc = beta[cc];
        for (int p = tid; p < cntB[cc]; p += 1024) Sb[cc*4096 + p] += bc;
    }
    __syncthreads();

    for (int lev = 0; lev < 2; ++lev) {
        const int pairs = 2 >> lev;
        const int Wd = 4096 << lev;
        if (tid < pairs) {
            const int lbase = tid * 2 * Wd;
            const int rbase = lbase + Wd;
            int cl = cntB[(2*tid) << lev];
            int cr = cntB[(2*tid+1) << lev];
            int i = cl - 1, j = 0;
            int kLi = Hb[lbase + i];            double yLi = Sb[lbase + i];
            int kLm = 0;                        double yLm = 0.0;
            if (i > 0) { kLm = Hb[lbase + i - 1]; yLm = Sb[lbase + i - 1]; }
            int kRj = Hb[rbase];                double yRj = Sb[rbase];
            int kRn = 0;                        double yRn = 0.0;
            if (cr > 1) { kRn = Hb[rbase + 1]; yRn = Sb[rbase + 1]; }
            bool moved = true;
            while (moved) {
                moved = false;
                while (i > 0) {
                    double cr_ = (double)(kLi - kLm)*(yRj - yLm)
                               - (yLi - yLm)*(double)(kRj - kLm);
                    if (cr_ >= 0.0) {
                        --i; kLi = kLm; yLi = yLm;
                        if (i > 0) { kLm = Hb[lbase + i - 1]; yLm = Sb[lbase + i - 1]; }
                        moved = true;
                    } else break;
                }
                while (j < cr - 1) {
                    double cr_ = (double)(kRj - kLi)*(yRn - yLi)
                               - (yRj - yLi)*(double)(kRn - kLi);
                    if (cr_ >= 0.0) {
                        ++j; kRj = kRn; yRj = yRn;
                        if (j < cr - 1) { kRn = Hb[rbase + j + 1]; yRn = Sb[rbase + j + 1]; }
                        moved = true;
                    } else break;
                }
            }
            tiS[tid] = i; tjS[tid] = j; crS[tid] = cr;
            cntB[(2*tid) << lev] = (i + 1) + (cr - j);
        }
        __syncthreads();
        const int tpp = (lev == 0) ? 512 : 1024;
        const int p = tid / tpp;
        const int q = tid % tpp;
        int hv[8]; double sv[8];
        int len = 0, srcb = 0, dstb = 0;
        if (p < pairs) {
            const int lbase = p * 2 * Wd;
            const int rbase = lbase + Wd;
            const int i = tiS[p], j = tjS[p], cr = crS[p];
            len = cr - j;
            srcb = rbase + j;
            dstb = lbase + i + 1;
            #pragma unroll
            for (int t2 = 0; t2 < 8; ++t2) {
                int e2 = q + t2 * tpp;
                if (e2 < len) { hv[t2] = Hb[srcb + e2]; sv[t2] = Sb[srcb + e2]; }
            }
        }
        __syncthreads();
        if (p < pairs) {
            #pragma unroll
            for (int t2 = 0; t2 < 8; ++t2) {
                int e2 = q + t2 * tpp;
                if (e2 < len) { Hb[dstb + e2] = hv[t2]; Sb[dstb + e2] = sv[t2]; }
            }
        }
        __syncthreads();
    }

    if (tid == 0) {
        const double total = beta[4];
        int out = cntB[0];
        while (out >= 2) {
            int ka = Hb[out - 2], kb2 = Hb[out - 1];
            double ya = Sb[out - 2], yb = Sb[out - 1];
            double cr_ = (double)(kb2 - ka)*(total - ya) - (yb - ya)*(double)(NR - ka);
            if (cr_ >= 0.0) --out;
            else break;
        }
        Hb[out] = NR; Sb[out] = total;
        cntB[0] = out + 1;
    }
    __syncthreads();

    // ---- outputs: 16 rows per thread, lockstep batched search ----
    const int m = cntB[0];
    const int cap = capp[0];
    const u64* kbat = keys + (size_t)b * NR;
    int lo_[16], hi_[16];
    #pragma unroll
    for (int r = 0; r < 16; ++r) { lo_[r] = 0; hi_[r] = m - 1; }
    for (int step = 0; step < 15; ++step) {
        int hm[16];
        #pragma unroll
        for (int r = 0; r < 16; ++r)
            if (hi_[r] - lo_[r] > 1) hm[r] = Hb[(lo_[r] + hi_[r]) >> 1];
        #pragma unroll
        for (int r = 0; r < 16; ++r) {
            if (hi_[r] - lo_[r] > 1) {
                int mid = (lo_[r] + hi_[r]) >> 1;
                int i = tid + (r << 10);
                if (hm[r] <= i) lo_[r] = mid; else hi_[r] = mid;
            }
        }
    }
    #pragma unroll 1
    for (int r = 0; r < 16; ++r) {
        const int i = tid + (r << 10);
        int ka = Hb[lo_[r]], kb2 = Hb[lo_[r] + 1];
        double slope = (Sb[lo_[r] + 1] - Sb[lo_[r]]) / (double)(kb2 - ka);
        u64 key = kbat[i];
        float s_i = (u2f((unsigned)(key >> 32)) - mn) * scale;
        float primal = (float)((double)s_i - slope);
        int idx = (int)(key & 0xffffffffu);
        out_soft[(size_t)b * NR + idx] = primal;
        int rank = (NR - 1) - i;
        out_bins[(size_t)b * NR + idx] = (float)(rank / cap + 1);
    }
}

extern "C" void kernel_launch(void* const* d_in, const int* in_sizes, int n_in,
                              void* d_out, int out_size, void* d_ws, size_t ws_size,
                              hipStream_t stream)
{
    const float* table = (const float*)d_in[0];
    const float* ln1_g = (const float*)d_in[1];
    const float* ln1_b = (const float*)d_in[2];
    const float* W1    = (const float*)d_in[3];
    const float* b1    = (const float*)d_in[4];
    const float* ln2_g = (const float*)d_in[5];
    const float* ln2_b = (const float*)d_in[6];
    const float* W2    = (const float*)d_in[7];
    const float* b2    = (const float*)d_in[8];
    const int*   cap   = (const int*)d_in[9];

    u64*      keys   = (u64*)d_ws;                    // TOT u64   (4 MiB)
    double*   Svg    = (double*)(keys + TOT);         // TOT f64   (4 MiB)
    double*   sumg   = Svg + TOT;                     // 128 f64
    float*    W1g    = (float*)(sumg + 128);          // 4096 f32
    float*    consts = W1g + NF*NH;                   // 64 f32
    unsigned* mnmx   = (unsigned*)(consts + 64);      // 64 u32
    unsigned* done   = mnmx + 64;                     // 32 u32
    int*      Hg     = (int*)(done + 32);             // TOT i32   (2 MiB)
    int*      cntg   = Hg + TOT;                      // 128 i32

    float* out_soft = (float*)d_out;
    float* out_bins = ((float*)d_out) + TOT;

    k_prep<<<1, 256, 0, stream>>>(ln1_g, ln1_b, W1, b1, ln2_g, ln2_b, W2, b2,
                                  W1g, consts, mnmx, done);
    k_scores<<<TOT/RPB, 256, 0, stream>>>(table, W1g, consts, keys, mnmx);
    k_sort_local<<<TOT/4096, 1024, 0, stream>>>(keys);   // k <= 4096
    k_mid8<<<TOT/8192, 1024, 0, stream>>>(keys);         // k = 8192 complete
    k_cross16<<<TOT/1024, 256, 0, stream>>>(keys);       // k=16384, j=8192,4096
    k_hullAB<<<NB*4, 1024, 0, stream>>>(keys, mnmx, cap, Hg, Svg, cntg, sumg,
                                        done, out_soft, out_bins);
}

// Round 11
// 300.456 us; speedup vs baseline: 1.1471x; 1.1471x over previous
//
#include <hip/hip_runtime.h>

#define NB 32
#define NR 16384
#define NF 256
#define NH 16
#define TOT (NB*NR)
#define RPB 256      // rows per block in k_scores
#define KC 32        // K-chunk
#define LSTR 33      // LDS row stride
#define SEGP 16386   // per-batch stride of segment arrays

typedef unsigned long long u64;

__device__ __forceinline__ unsigned int f2u(float f) {
    unsigned int u = __float_as_uint(f);
    return (u & 0x80000000u) ? ~u : (u | 0x80000000u);
}
__device__ __forceinline__ float u2f(unsigned int s) {
    unsigned int u = (s & 0x80000000u) ? (s ^ 0x80000000u) : ~s;
    return __uint_as_float(u);
}

// ---------------- Kernel 0: fold constants + init mnmx --------------------
__global__ __launch_bounds__(256) void k_prep(
    const float* __restrict__ ln1_g, const float* __restrict__ ln1_b,
    const float* __restrict__ W1, const float* __restrict__ b1,
    const float* __restrict__ ln2_g, const float* __restrict__ ln2_b,
    const float* __restrict__ W2, const float* __restrict__ b2,
    float* __restrict__ W1g, float* __restrict__ consts,
    unsigned* __restrict__ mnmx)
{
    __shared__ float redc[16][16];
    __shared__ float redu[16][16];
    const int t = threadIdx.x;
    for (int e = t; e < NF*NH; e += 256) {
        int k = e >> 4;
        W1g[e] = ln1_g[k] * W1[e];
    }
    if (t < NB) { mnmx[2*t] = 0u; mnmx[2*t + 1] = 0xFFFFFFFFu; }
    const int h = t & 15, kp = t >> 4;
    float pc = 0.f, pu = 0.f;
    #pragma unroll
    for (int r = 0; r < 16; ++r) {
        int k = kp*16 + r;
        float w = W1[k*NH + h];
        pc += ln1_b[k] * w;
        pu += ln1_g[k] * w;
    }
    redc[kp][h] = pc; redu[kp][h] = pu;
    __syncthreads();
    if (t < 16) {
        float sc = 0.f, su = 0.f;
        #pragma unroll
        for (int r = 0; r < 16; ++r) { sc += redc[r][t]; su += redu[r][t]; }
        consts[t]      = sc + b1[t];
        consts[16 + t] = su;
        consts[32 + t] = ln2_g[t] * W2[t];
    }
    if (t == 0) {
        float U2 = 0.f, C2 = b2[0];
        for (int hh = 0; hh < 16; ++hh) {
            U2 += ln2_g[hh] * W2[hh];
            C2 += ln2_b[hh] * W2[hh];
        }
        consts[48] = U2;
        consts[49] = C2;
    }
}

// ---------------- Kernel 1: thread-per-row fused scores (early-issue) -----
__global__ __launch_bounds__(256) void k_scores(
    const float* __restrict__ table,
    const float* __restrict__ W1g,
    const float* __restrict__ consts,
    u64* __restrict__ keys, unsigned* __restrict__ mnmx)
{
    __shared__ float xt[RPB * LSTR];   // 33,792 B
    __shared__ unsigned redmx[4], redmn[4];
    const int t = threadIdx.x;
    const size_t rowBase = (size_t)blockIdx.x * RPB;
    const int bb = blockIdx.x >> 6;    // batch (64 blocks per batch)
    const float4* __restrict__ Wg4 = (const float4*)W1g;

    float dx[16];
    #pragma unroll
    for (int h = 0; h < 16; ++h) dx[h] = 0.f;
    float sum = 0.f, ssq = 0.f;

    // prologue: issue chunk 0 loads
    float4 v[8];
    #pragma unroll
    for (int p = 0; p < 8; ++p) {
        int q = p*256 + t;
        int r = q >> 3, cg = q & 7;
        v[p] = *(const float4*)(table + (rowBase + r)*NF + cg*4);
    }

    for (int c = 0; c < NF/KC; ++c) {
        __syncthreads();   // prev chunk's xt reads complete
        #pragma unroll
        for (int p = 0; p < 8; ++p) {
            int q = p*256 + t;
            int r = q >> 3, cg = q & 7;
            float* dst = xt + r*LSTR + cg*4;
            dst[0] = v[p].x; dst[1] = v[p].y; dst[2] = v[p].z; dst[3] = v[p].w;
        }
        __syncthreads();
        // issue NEXT chunk's loads before compute: HBM latency hides
        if (c + 1 < NF/KC) {
            #pragma unroll
            for (int p = 0; p < 8; ++p) {
                int q = p*256 + t;
                int r = q >> 3, cg = q & 7;
                v[p] = *(const float4*)(table + (rowBase + r)*NF + (c+1)*KC + cg*4);
            }
        }

        const float* __restrict__ xr = xt + t*LSTR;
        #pragma unroll 4
        for (int k = 0; k < KC; ++k) {
            const int kk = c*KC + k;
            float x = xr[k];
            float4 w0 = Wg4[kk*4+0];   // uniform -> s_load
            float4 w1 = Wg4[kk*4+1];
            float4 w2 = Wg4[kk*4+2];
            float4 w3 = Wg4[kk*4+3];
            sum += x;
            ssq = fmaf(x, x, ssq);
            dx[ 0] = fmaf(x, w0.x, dx[ 0]);
            dx[ 1] = fmaf(x, w0.y, dx[ 1]);
            dx[ 2] = fmaf(x, w0.z, dx[ 2]);
            dx[ 3] = fmaf(x, w0.w, dx[ 3]);
            dx[ 4] = fmaf(x, w1.x, dx[ 4]);
            dx[ 5] = fmaf(x, w1.y, dx[ 5]);
            dx[ 6] = fmaf(x, w1.z, dx[ 6]);
            dx[ 7] = fmaf(x, w1.w, dx[ 7]);
            dx[ 8] = fmaf(x, w2.x, dx[ 8]);
            dx[ 9] = fmaf(x, w2.y, dx[ 9]);
            dx[10] = fmaf(x, w2.z, dx[10]);
            dx[11] = fmaf(x, w2.w, dx[11]);
            dx[12] = fmaf(x, w3.x, dx[12]);
            dx[13] = fmaf(x, w3.y, dx[13]);
            dx[14] = fmaf(x, w3.z, dx[14]);
            dx[15] = fmaf(x, w3.w, dx[15]);
        }
    }

    const float mu   = sum * (1.f/NF);
    const float var  = ssq * (1.f/NF) - mu*mu;
    const float rstd = rsqrtf(var + 1e-5f);
    float s2 = 0.f, q2 = 0.f, dh = 0.f;
    #pragma unroll
    for (int h = 0; h < 16; ++h) {
        float hv = rstd * (dx[h] - mu * consts[16 + h]) + consts[h];
        hv = fmaxf(hv, 0.f);
        s2 += hv;
        q2 = fmaf(hv, hv, q2);
        dh = fmaf(hv, consts[32 + h], dh);
    }
    const float mu2   = s2 * (1.f/NH);
    const float var2  = q2 * (1.f/NH) - mu2*mu2;
    const float rstd2 = rsqrtf(var2 + 1e-5f);
    const float sc    = rstd2 * (dh - mu2 * consts[48]) + consts[49];

    const size_t row = rowBase + t;
    const unsigned k32 = f2u(sc);
    keys[row] = ((u64)k32 << 32) | (u64)(row & (NR-1));

    unsigned wmx = k32, wmn = k32;
    #pragma unroll
    for (int m = 32; m >= 1; m >>= 1) {
        wmx = max(wmx, (unsigned)__shfl_xor((int)wmx, m, 64));
        wmn = min(wmn, (unsigned)__shfl_xor((int)wmn, m, 64));
    }
    const int lane = t & 63, wid = t >> 6;
    if (lane == 0) { redmx[wid] = wmx; redmn[wid] = wmn; }
    __syncthreads();
    if (t == 0) {
        unsigned bx = redmx[0], bn = redmn[0];
        #pragma unroll
        for (int w = 1; w < 4; ++w) { bx = max(bx, redmx[w]); bn = min(bn, redmn[w]); }
        atomicMax(&mnmx[2*bb], bx);
        atomicMin(&mnmx[2*bb + 1], bn);
    }
}

// ---------------- Kernel 2a: full bitonic sort of 4096-chunks -------------
__global__ __launch_bounds__(1024) void k_sort_local(u64* __restrict__ keys) {
    __shared__ u64 sk[4096];
    const int base_g = blockIdx.x * 4096;
    const int tid = threadIdx.x;
    #pragma unroll
    for (int it = 0; it < 4; ++it) sk[tid + it*1024] = keys[base_g + tid + it*1024];
    __syncthreads();
    for (int k = 2; k <= 4096; k <<= 1) {
        for (int j = k >> 1; j > 0; j >>= 1) {
            int ii[2]; u64 a[2], c[2];
            #pragma unroll
            for (int it = 0; it < 2; ++it) {
                int q = tid + it*1024;
                int i = ((q & ~(j-1)) << 1) | (q & (j-1));
                ii[it] = i;
                a[it] = sk[i]; c[it] = sk[i | j];
            }
            #pragma unroll
            for (int it = 0; it < 2; ++it) {
                int gi = (base_g + ii[it]) & (NR - 1);
                bool dir = ((gi & k) == 0);
                if ((c[it] > a[it]) == dir) { sk[ii[it]] = c[it]; sk[ii[it] | j] = a[it]; }
            }
            __syncthreads();
        }
    }
    #pragma unroll
    for (int it = 0; it < 4; ++it) keys[base_g + tid + it*1024] = sk[tid + it*1024];
}

// ---------------- Kernel 2b: within-4096-chunk tail (j<=2048) of stage K --
__global__ __launch_bounds__(1024) void k_mtail(u64* __restrict__ keys, int K) {
    __shared__ u64 sk[4096];
    const int base_g = blockIdx.x * 4096;
    const int tid = threadIdx.x;
    #pragma unroll
    for (int it = 0; it < 4; ++it) sk[tid + it*1024] = keys[base_g + tid + it*1024];
    const bool dir = (((base_g & (NR-1)) & K) == 0);
    __syncthreads();
    for (int j = 2048; j >= 1; j >>= 1) {
        int ii[2]; u64 a[2], c[2];
        #pragma unroll
        for (int it = 0; it < 2; ++it) {
            int q = tid + it*1024;
            int i = ((q & ~(j-1)) << 1) | (q & (j-1));
            ii[it] = i;
            a[it] = sk[i]; c[it] = sk[i | j];
        }
        #pragma unroll
        for (int it = 0; it < 2; ++it) {
            if ((c[it] > a[it]) == dir) { sk[ii[it]] = c[it]; sk[ii[it] | j] = a[it]; }
        }
        __syncthreads();
    }
    #pragma unroll
    for (int it = 0; it < 4; ++it) keys[base_g + tid + it*1024] = sk[tid + it*1024];
}

// ---------------- Kernel 2c: cross-chunk global pair pass -----------------
__global__ __launch_bounds__(256) void k_gpass(u64* __restrict__ keys, int k, int j) {
    int gt = blockIdx.x * 256 + threadIdx.x;
    int b  = gt >> 13;
    int t  = gt & 8191;
    int i  = ((t & ~(j-1)) << 1) | (t & (j-1));
    bool dir = ((i & k) == 0);
    u64* kb = keys + (size_t)b * NR;
    u64 a = kb[i], c = kb[i | j];
    if ((c > a) == dir) { kb[i] = c; kb[i | j] = a; }
}

// ---------------- Kernel 2d: stage k=16384 phases j=8192,4096 (registers) -
__global__ __launch_bounds__(256) void k_cross16(u64* __restrict__ keys) {
    const int gt = blockIdx.x * 256 + threadIdx.x;   // TOT/4 threads
    const int b = gt >> 12;
    const int c = gt & 4095;
    u64* kb = keys + (size_t)b * NR + c;
    u64 e0 = kb[0], e1 = kb[4096], e2 = kb[8192], e3 = kb[12288];
    u64 t;
    // j=8192 (descending)
    if (e2 > e0) { t = e0; e0 = e2; e2 = t; }
    if (e3 > e1) { t = e1; e1 = e3; e3 = t; }
    // j=4096
    if (e1 > e0) { t = e0; e0 = e1; e1 = t; }
    if (e3 > e2) { t = e2; e2 = e3; e3 = t; }
    kb[0] = e0; kb[4096] = e1; kb[8192] = e2; kb[12288] = e3;
}

// ---------------- Kernel 3a: final tail + chunk scan + chunk hull ---------
__global__ __launch_bounds__(1024) void k_hullA(
    u64* __restrict__ keys, const unsigned* __restrict__ mnmx,
    int* __restrict__ Hg, double* __restrict__ Svg,
    int* __restrict__ cntg, double* __restrict__ sumg)
{
    __shared__ __align__(16) char smem[32768 + 16384 + 128 + 1024 + 3*512];
    u64*    sk  = (u64*)smem;            // [4096] sort phase
    double* S   = (double*)smem;         // [4096] scan phase (overlay)
    int*    H   = (int*)(smem + 32768);  // [4096]
    double* Wt  = (double*)(smem + 32768 + 16384);          // [16]
    int*    cnt = (int*)(smem + 32768 + 16384 + 128);       // [256]
    int*    ti  = (int*)(smem + 32768 + 16384 + 128 + 1024);
    int*    tj  = (int*)(smem + 32768 + 16384 + 128 + 1024 + 512);
    int*    crA = (int*)(smem + 32768 + 16384 + 128 + 1024 + 1024);

    const int blk = blockIdx.x;
    const int b = blk >> 2, c = blk & 3;
    const int tid = threadIdx.x, lane = tid & 63, wid = tid >> 6;
    u64* kg = keys + (size_t)b * NR + c * 4096;

    // load + final bitonic tail (stage k=16384, j<=2048, dir = descending)
    #pragma unroll
    for (int it = 0; it < 4; ++it) sk[tid + it*1024] = kg[tid + it*1024];
    __syncthreads();
    for (int j = 2048; j >= 1; j >>= 1) {
        int ii[2]; u64 a[2], cc[2];
        #pragma unroll
        for (int it = 0; it < 2; ++it) {
            int q = tid + it*1024;
            int i = ((q & ~(j-1)) << 1) | (q & (j-1));
            ii[it] = i;
            a[it] = sk[i]; cc[it] = sk[i | j];
        }
        #pragma unroll
        for (int it = 0; it < 2; ++it) {
            if (cc[it] > a[it]) { sk[ii[it]] = cc[it]; sk[ii[it] | j] = a[it]; }
        }
        __syncthreads();
    }

    // writeback sorted chunk; compute y and per-thread local scan (4 elems)
    const float mx = u2f(mnmx[2*b]);
    const float mn = u2f(mnmx[2*b + 1]);
    const float scale = 10000.0f / (mx - mn);
    const int gofs = c * 4096;
    const int b4 = tid * 4;

    u64 kv[4];
    #pragma unroll
    for (int r = 0; r < 4; ++r) kv[r] = sk[b4 + r];
    #pragma unroll
    for (int it = 0; it < 4; ++it) kg[tid + it*1024] = sk[tid + it*1024];

    double loc[4];
    double acc = 0.0;
    #pragma unroll
    for (int r = 0; r < 4; ++r) {
        int ig = gofs + b4 + r;
        float s_i = (u2f((unsigned)(kv[r] >> 32)) - mn) * scale;
        acc += (double)s_i - (double)(NR - ig);
        loc[r] = acc;
    }
    __syncthreads();     // ALL sk reads complete before S overlay writes

    double v = acc;
    #pragma unroll
    for (int d = 1; d < 64; d <<= 1) {
        double o = __shfl_up(v, d, 64);
        if (lane >= d) v += o;
    }
    if (lane == 63) Wt[wid] = v;
    __syncthreads();
    if (tid < 16) {
        double w = Wt[tid];
        #pragma unroll
        for (int d = 1; d < 16; d <<= 1) {
            double o = __shfl_up(w, d, 16);
            if ((tid & 15) >= d) w += o;
        }
        Wt[tid] = w;
    }
    __syncthreads();
    const double wbase = (wid == 0) ? 0.0 : Wt[wid - 1];
    const double excl = wbase + (v - acc);
    #pragma unroll
    for (int r = 0; r < 4; ++r) S[b4 + r] = excl + loc[r];
    __syncthreads();
    if (tid == 0) sumg[blk] = S[4095];

    #define SVA(k) ((k) == 0 ? 0.0 : S[(k)-1])

    // level-0: 16-point hulls on threads 0..255, stack top reg-cached
    if (tid < 256) {
        const int base16 = tid * 16;
        int out = 0;
        int k1 = 0, k2 = 0; double y1 = 0.0, y2 = 0.0;
        #pragma unroll 1
        for (int r = 0; r < 16; ++r) {
            int k = base16 + r;
            double yk = SVA(k);
            while (out >= 2) {
                double cr_ = (double)(k1 - k2)*(yk - y2) - (y1 - y2)*(double)(k - k2);
                if (cr_ >= 0.0) {
                    --out; k1 = k2; y1 = y2;
                    if (out >= 2) { k2 = H[base16 + out - 2]; y2 = SVA(k2); }
                } else break;
            }
            H[base16 + out] = k;
            k2 = k1; y2 = y1; k1 = k; y1 = yk;
            ++out;
        }
        cnt[tid] = out;
    }

    // 8 merge levels (256 -> 1)
    for (int lev = 0; lev < 8; ++lev) {
        __syncthreads();
        const int pairs = 128 >> lev;
        const int Wd = 16 << lev;
        if (tid < pairs) {
            const int lbase = tid * 2 * Wd;
            const int rbase = lbase + Wd;
            int cl = cnt[(2*tid) << lev];
            int cr = cnt[(2*tid+1) << lev];
            int i = cl - 1, j = 0;
            int kLi = H[lbase + i];            double yLi = SVA(kLi);
            int kLm = 0;                       double yLm = 0.0;
            if (i > 0) { kLm = H[lbase + i - 1]; yLm = SVA(kLm); }
            int kRj = H[rbase];                double yRj = SVA(kRj);
            int kRn = 0;                       double yRn = 0.0;
            if (cr > 1) { kRn = H[rbase + 1]; yRn = SVA(kRn); }
            bool moved = true;
            while (moved) {
                moved = false;
                while (i > 0) {
                    double cr_ = (double)(kLi - kLm)*(yRj - yLm)
                               - (yLi - yLm)*(double)(kRj - kLm);
                    if (cr_ >= 0.0) {
                        --i; kLi = kLm; yLi = yLm;
                        if (i > 0) { kLm = H[lbase + i - 1]; yLm = SVA(kLm); }
                        moved = true;
                    } else break;
                }
                while (j < cr - 1) {
                    double cr_ = (double)(kRj - kLi)*(yRn - yLi)
                               - (yRj - yLi)*(double)(kRn - kLi);
                    if (cr_ >= 0.0) {
                        ++j; kRj = kRn; yRj = yRn;
                        if (j < cr - 1) { kRn = H[rbase + j + 1]; yRn = SVA(kRn); }
                        moved = true;
                    } else break;
                }
            }
            ti[tid] = i; tj[tid] = j; crA[tid] = cr;
            cnt[(2*tid) << lev] = (i + 1) + (cr - j);
        }
        __syncthreads();
        const int tpp = 8 << lev;
        const int p = tid / tpp;
        const int q = tid % tpp;
        int vals[8];
        int len = 0, srcb = 0, dstb = 0;
        if (p < pairs) {
            const int lbase = p * 2 * Wd;
            const int rbase = lbase + Wd;
            const int i = ti[p], j = tj[p], cr = crA[p];
            len = cr - j;
            srcb = rbase + j;
            dstb = lbase + i + 1;
            #pragma unroll
            for (int t2 = 0; t2 < 8; ++t2) {
                int e2 = q + t2 * tpp;
                if (e2 < len) vals[t2] = H[srcb + e2];
            }
        }
        __syncthreads();
        if (p < pairs) {
            #pragma unroll
            for (int t2 = 0; t2 < 8; ++t2) {
                int e2 = q + t2 * tpp;
                if (e2 < len) H[dstb + e2] = vals[t2];
            }
        }
        __syncthreads();
    }

    // write chunk hull (global k, local f64 S at points)
    const int m = cnt[0];
    for (int p = tid; p < m; p += 1024) {
        int k = H[p];
        Hg[(size_t)blk * 4096 + p]  = k + gofs;
        Svg[(size_t)blk * 4096 + p] = SVA(k);
    }
    if (tid == 0) cntg[blk] = m;
    #undef SVA
}

// ---------------- Kernel 3b: merge 4 chunk hulls per batch + segments -----
__global__ __launch_bounds__(1024) void k_hullB(
    const double* __restrict__ sumg,
    int* __restrict__ Hg, double* __restrict__ Svg,
    const int* __restrict__ cntg,
    int* __restrict__ segk, float* __restrict__ segs, int* __restrict__ mseg)
{
    __shared__ int cnt[4];
    __shared__ int tiS[2], tjS[2], crS[2];
    __shared__ double beta[5];
    const int b = blockIdx.x;
    const int tid = threadIdx.x;
    int*    Hb = Hg  + (size_t)b * NR;
    double* Sb = Svg + (size_t)b * NR;

    if (tid < 4) cnt[tid] = cntg[4*b + tid];
    if (tid == 0) {
        double s = 0.0;
        #pragma unroll
        for (int c = 0; c < 4; ++c) { beta[c] = s; s += sumg[4*b + c]; }
        beta[4] = s;
    }
    __syncthreads();

    #pragma unroll 1
    for (int c = 0; c < 4; ++c) {
        const double bc = beta[c];
        for (int p = tid; p < cnt[c]; p += 1024) Sb[c*4096 + p] += bc;
    }
    __syncthreads();

    for (int lev = 0; lev < 2; ++lev) {
        const int pairs = 2 >> lev;
        const int Wd = 4096 << lev;
        if (tid < pairs) {
            const int lbase = tid * 2 * Wd;
            const int rbase = lbase + Wd;
            int cl = cnt[(2*tid) << lev];
            int cr = cnt[(2*tid+1) << lev];
            int i = cl - 1, j = 0;
            int kLi = Hb[lbase + i];            double yLi = Sb[lbase + i];
            int kLm = 0;                        double yLm = 0.0;
            if (i > 0) { kLm = Hb[lbase + i - 1]; yLm = Sb[lbase + i - 1]; }
            int kRj = Hb[rbase];                double yRj = Sb[rbase];
            int kRn = 0;                        double yRn = 0.0;
            if (cr > 1) { kRn = Hb[rbase + 1]; yRn = Sb[rbase + 1]; }
            bool moved = true;
            while (moved) {
                moved = false;
                while (i > 0) {
                    double cr_ = (double)(kLi - kLm)*(yRj - yLm)
                               - (yLi - yLm)*(double)(kRj - kLm);
                    if (cr_ >= 0.0) {
                        --i; kLi = kLm; yLi = yLm;
                        if (i > 0) { kLm = Hb[lbase + i - 1]; yLm = Sb[lbase + i - 1]; }
                        moved = true;
                    } else break;
                }
                while (j < cr - 1) {
                    double cr_ = (double)(kRj - kLi)*(yRn - yLi)
                               - (yRj - yLi)*(double)(kRn - kLi);
                    if (cr_ >= 0.0) {
                        ++j; kRj = kRn; yRj = yRn;
                        if (j < cr - 1) { kRn = Hb[rbase + j + 1]; yRn = Sb[rbase + j + 1]; }
                        moved = true;
                    } else break;
                }
            }
            tiS[tid] = i; tjS[tid] = j; crS[tid] = cr;
            cnt[(2*tid) << lev] = (i + 1) + (cr - j);
        }
        __syncthreads();
        const int tpp = (lev == 0) ? 512 : 1024;
        const int p = tid / tpp;
        const int q = tid % tpp;
        int hv[8]; double sv[8];
        int len = 0, srcb = 0, dstb = 0;
        if (p < pairs) {
            const int lbase = p * 2 * Wd;
            const int rbase = lbase + Wd;
            const int i = tiS[p], j = tjS[p], cr = crS[p];
            len = cr - j;
            srcb = rbase + j;
            dstb = lbase + i + 1;
            #pragma unroll
            for (int t2 = 0; t2 < 8; ++t2) {
                int e2 = q + t2 * tpp;
                if (e2 < len) { hv[t2] = Hb[srcb + e2]; sv[t2] = Sb[srcb + e2]; }
            }
        }
        __syncthreads();
        if (p < pairs) {
            #pragma unroll
            for (int t2 = 0; t2 < 8; ++t2) {
                int e2 = q + t2 * tpp;
                if (e2 < len) { Hb[dstb + e2] = hv[t2]; Sb[dstb + e2] = sv[t2]; }
            }
        }
        __syncthreads();
    }

    if (tid == 0) {
        const double total = beta[4];
        int out = cnt[0];
        while (out >= 2) {
            int ka = Hb[out - 2], kb2 = Hb[out - 1];
            double ya = Sb[out - 2], yb = Sb[out - 1];
            double cr_ = (double)(kb2 - ka)*(total - ya) - (yb - ya)*(double)(NR - ka);
            if (cr_ >= 0.0) --out;
            else break;
        }
        Hb[out] = NR; Sb[out] = total;
        cnt[0] = out + 1;
    }
    __syncthreads();

    const int m = cnt[0];
    for (int p = tid; p < m - 1; p += 1024) {
        int ka = Hb[p], kb2 = Hb[p + 1];
        segk[(size_t)b * SEGP + p] = ka;
        segs[(size_t)b * SEGP + p] = (float)((Sb[p + 1] - Sb[p]) / (double)(kb2 - ka));
    }
    if (tid == 0) mseg[b] = m;
}

// ---------------- Kernel 3c: outputs (full width) -------------------------
__global__ __launch_bounds__(256) void k_out(
    const u64* __restrict__ keys, const unsigned* __restrict__ mnmx,
    const int* __restrict__ capp,
    const int* __restrict__ segk, const float* __restrict__ segs,
    const int* __restrict__ mseg,
    float* __restrict__ out_soft, float* __restrict__ out_bins)
{
    const int gb = blockIdx.x;           // 512 blocks: 16 per batch
    const int b = gb >> 4, part = gb & 15;
    const int tid = threadIdx.x;
    const int m = mseg[b];
    const float mx = u2f(mnmx[2*b]);
    const float mn = u2f(mnmx[2*b + 1]);
    const float scale = 10000.0f / (mx - mn);
    const int cap = capp[0];
    const int base = part * 1024;
    const int* __restrict__ sk2 = segk + (size_t)b * SEGP;
    const float* __restrict__ ss2 = segs + (size_t)b * SEGP;

    int lo[4], hi[4];
    #pragma unroll
    for (int r = 0; r < 4; ++r) { lo[r] = 0; hi[r] = m - 1; }
    for (int step = 0; step < 14; ++step) {
        int hm[4];
        #pragma unroll
        for (int r = 0; r < 4; ++r)
            if (hi[r] - lo[r] > 1) hm[r] = sk2[(lo[r] + hi[r]) >> 1];
        #pragma unroll
        for (int r = 0; r < 4; ++r) {
            if (hi[r] - lo[r] > 1) {
                int mid = (lo[r] + hi[r]) >> 1;
                int i = base + tid + (r << 8);
                if (hm[r] <= i) lo[r] = mid; else hi[r] = mid;
            }
        }
    }
    #pragma unroll
    for (int r = 0; r < 4; ++r) {
        const int i = base + tid + (r << 8);
        u64 key = keys[(size_t)b * NR + i];
        float s_i = (u2f((unsigned)(key >> 32)) - mn) * scale;
        float primal = s_i - ss2[lo[r]];
        int idx = (int)(key & 0xffffffffu);
        out_soft[(size_t)b * NR + idx] = primal;
        int rank = (NR - 1) - i;
        out_bins[(size_t)b * NR + idx] = (float)(rank / cap + 1);
    }
}

extern "C" void kernel_launch(void* const* d_in, const int* in_sizes, int n_in,
                              void* d_out, int out_size, void* d_ws, size_t ws_size,
                              hipStream_t stream)
{
    const float* table = (const float*)d_in[0];
    const float* ln1_g = (const float*)d_in[1];
    const float* ln1_b = (const float*)d_in[2];
    const float* W1    = (const float*)d_in[3];
    const float* b1    = (const float*)d_in[4];
    const float* ln2_g = (const float*)d_in[5];
    const float* ln2_b = (const float*)d_in[6];
    const float* W2    = (const float*)d_in[7];
    const float* b2    = (const float*)d_in[8];
    const int*   cap   = (const int*)d_in[9];

    u64*      keys   = (u64*)d_ws;                    // TOT u64   (4 MiB)
    double*   Svg    = (double*)(keys + TOT);         // TOT f64   (4 MiB)
    double*   sumg   = Svg + TOT;                     // 128 f64
    float*    W1g    = (float*)(sumg + 128);          // 4096 f32
    float*    consts = W1g + NF*NH;                   // 64 f32
    unsigned* mnmx   = (unsigned*)(consts + 64);      // 64 u32
    int*      Hg     = (int*)(mnmx + 64);             // TOT i32   (2 MiB)
    int*      cntg   = Hg + TOT;                      // 128 i32
    int*      segk   = cntg + 128;                    // NB*SEGP i32
    float*    segs   = (float*)(segk + NB*SEGP);      // NB*SEGP f32
    int*      mseg   = (int*)(segs + NB*SEGP);        // NB i32

    float* out_soft = (float*)d_out;
    float* out_bins = ((float*)d_out) + TOT;

    k_prep<<<1, 256, 0, stream>>>(ln1_g, ln1_b, W1, b1, ln2_g, ln2_b, W2, b2,
                                  W1g, consts, mnmx);
    k_scores<<<TOT/RPB, 256, 0, stream>>>(table, W1g, consts, keys, mnmx);

    k_sort_local<<<TOT/4096, 1024, 0, stream>>>(keys);         // k <= 4096
    k_gpass<<<TOT/512, 256, 0, stream>>>(keys, 8192, 4096);    // k=8192, j=4096
    k_mtail<<<TOT/4096, 1024, 0, stream>>>(keys, 8192);        // k=8192 tail
    k_cross16<<<TOT/1024, 256, 0, stream>>>(keys);             // k=16384, j=8192,4096

    k_hullA<<<NB*4, 1024, 0, stream>>>(keys, mnmx, Hg, Svg, cntg, sumg);
    k_hullB<<<NB, 1024, 0, stream>>>(sumg, Hg, Svg, cntg, segk, segs, mseg);
    k_out<<<NB*16, 256, 0, stream>>>(keys, mnmx, cap, segk, segs, mseg,
                                     out_soft, out_bins);
}

// Round 12
// 293.045 us; speedup vs baseline: 1.1761x; 1.0253x over previous
//
#include <hip/hip_runtime.h>

#define NB 32
#define NR 16384
#define NF 256
#define NH 16
#define TOT (NB*NR)
#define RPB 256      // rows per block in k_scores
#define KC 32        // K-chunk
#define LSTR 33      // LDS row stride
#define SEGP 16386   // per-batch stride of segment arrays

typedef unsigned long long u64;

__device__ __forceinline__ unsigned int f2u(float f) {
    unsigned int u = __float_as_uint(f);
    return (u & 0x80000000u) ? ~u : (u | 0x80000000u);
}
__device__ __forceinline__ float u2f(unsigned int s) {
    unsigned int u = (s & 0x80000000u) ? (s ^ 0x80000000u) : ~s;
    return __uint_as_float(u);
}

// ---------------- Kernel 0: fold constants + init mnmx --------------------
__global__ __launch_bounds__(256) void k_prep(
    const float* __restrict__ ln1_g, const float* __restrict__ ln1_b,
    const float* __restrict__ W1, const float* __restrict__ b1,
    const float* __restrict__ ln2_g, const float* __restrict__ ln2_b,
    const float* __restrict__ W2, const float* __restrict__ b2,
    float* __restrict__ W1g, float* __restrict__ consts,
    unsigned* __restrict__ mnmx)
{
    __shared__ float redc[16][16];
    __shared__ float redu[16][16];
    const int t = threadIdx.x;
    for (int e = t; e < NF*NH; e += 256) {
        int k = e >> 4;
        W1g[e] = ln1_g[k] * W1[e];
    }
    if (t < NB) { mnmx[2*t] = 0u; mnmx[2*t + 1] = 0xFFFFFFFFu; }
    const int h = t & 15, kp = t >> 4;
    float pc = 0.f, pu = 0.f;
    #pragma unroll
    for (int r = 0; r < 16; ++r) {
        int k = kp*16 + r;
        float w = W1[k*NH + h];
        pc += ln1_b[k] * w;
        pu += ln1_g[k] * w;
    }
    redc[kp][h] = pc; redu[kp][h] = pu;
    __syncthreads();
    if (t < 16) {
        float sc = 0.f, su = 0.f;
        #pragma unroll
        for (int r = 0; r < 16; ++r) { sc += redc[r][t]; su += redu[r][t]; }
        consts[t]      = sc + b1[t];
        consts[16 + t] = su;
        consts[32 + t] = ln2_g[t] * W2[t];
    }
    if (t == 0) {
        float U2 = 0.f, C2 = b2[0];
        for (int hh = 0; hh < 16; ++hh) {
            U2 += ln2_g[hh] * W2[hh];
            C2 += ln2_b[hh] * W2[hh];
        }
        consts[48] = U2;
        consts[49] = C2;
    }
}

// ---------------- Kernel 1: thread-per-row fused scores (early-issue) -----
__global__ __launch_bounds__(256) void k_scores(
    const float* __restrict__ table,
    const float* __restrict__ W1g,
    const float* __restrict__ consts,
    u64* __restrict__ keys, unsigned* __restrict__ mnmx)
{
    __shared__ float xt[RPB * LSTR];   // 33,792 B
    __shared__ unsigned redmx[4], redmn[4];
    const int t = threadIdx.x;
    const size_t rowBase = (size_t)blockIdx.x * RPB;
    const int bb = blockIdx.x >> 6;    // batch (64 blocks per batch)
    const float4* __restrict__ Wg4 = (const float4*)W1g;

    float dx[16];
    #pragma unroll
    for (int h = 0; h < 16; ++h) dx[h] = 0.f;
    float sum = 0.f, ssq = 0.f;

    // prologue: issue chunk 0 loads
    float4 v[8];
    #pragma unroll
    for (int p = 0; p < 8; ++p) {
        int q = p*256 + t;
        int r = q >> 3, cg = q & 7;
        v[p] = *(const float4*)(table + (rowBase + r)*NF + cg*4);
    }

    for (int c = 0; c < NF/KC; ++c) {
        __syncthreads();   // prev chunk's xt reads complete
        #pragma unroll
        for (int p = 0; p < 8; ++p) {
            int q = p*256 + t;
            int r = q >> 3, cg = q & 7;
            float* dst = xt + r*LSTR + cg*4;
            dst[0] = v[p].x; dst[1] = v[p].y; dst[2] = v[p].z; dst[3] = v[p].w;
        }
        __syncthreads();
        // issue NEXT chunk's loads before compute: HBM latency hides
        if (c + 1 < NF/KC) {
            #pragma unroll
            for (int p = 0; p < 8; ++p) {
                int q = p*256 + t;
                int r = q >> 3, cg = q & 7;
                v[p] = *(const float4*)(table + (rowBase + r)*NF + (c+1)*KC + cg*4);
            }
        }

        const float* __restrict__ xr = xt + t*LSTR;
        #pragma unroll 4
        for (int k = 0; k < KC; ++k) {
            const int kk = c*KC + k;
            float x = xr[k];
            float4 w0 = Wg4[kk*4+0];   // uniform -> s_load
            float4 w1 = Wg4[kk*4+1];
            float4 w2 = Wg4[kk*4+2];
            float4 w3 = Wg4[kk*4+3];
            sum += x;
            ssq = fmaf(x, x, ssq);
            dx[ 0] = fmaf(x, w0.x, dx[ 0]);
            dx[ 1] = fmaf(x, w0.y, dx[ 1]);
            dx[ 2] = fmaf(x, w0.z, dx[ 2]);
            dx[ 3] = fmaf(x, w0.w, dx[ 3]);
            dx[ 4] = fmaf(x, w1.x, dx[ 4]);
            dx[ 5] = fmaf(x, w1.y, dx[ 5]);
            dx[ 6] = fmaf(x, w1.z, dx[ 6]);
            dx[ 7] = fmaf(x, w1.w, dx[ 7]);
            dx[ 8] = fmaf(x, w2.x, dx[ 8]);
            dx[ 9] = fmaf(x, w2.y, dx[ 9]);
            dx[10] = fmaf(x, w2.z, dx[10]);
            dx[11] = fmaf(x, w2.w, dx[11]);
            dx[12] = fmaf(x, w3.x, dx[12]);
            dx[13] = fmaf(x, w3.y, dx[13]);
            dx[14] = fmaf(x, w3.z, dx[14]);
            dx[15] = fmaf(x, w3.w, dx[15]);
        }
    }

    const float mu   = sum * (1.f/NF);
    const float var  = ssq * (1.f/NF) - mu*mu;
    const float rstd = rsqrtf(var + 1e-5f);
    float s2 = 0.f, q2 = 0.f, dh = 0.f;
    #pragma unroll
    for (int h = 0; h < 16; ++h) {
        float hv = rstd * (dx[h] - mu * consts[16 + h]) + consts[h];
        hv = fmaxf(hv, 0.f);
        s2 += hv;
        q2 = fmaf(hv, hv, q2);
        dh = fmaf(hv, consts[32 + h], dh);
    }
    const float mu2   = s2 * (1.f/NH);
    const float var2  = q2 * (1.f/NH) - mu2*mu2;
    const float rstd2 = rsqrtf(var2 + 1e-5f);
    const float sc    = rstd2 * (dh - mu2 * consts[48]) + consts[49];

    const size_t row = rowBase + t;
    const unsigned k32 = f2u(sc);
    keys[row] = ((u64)k32 << 32) | (u64)(row & (NR-1));

    unsigned wmx = k32, wmn = k32;
    #pragma unroll
    for (int m = 32; m >= 1; m >>= 1) {
        wmx = max(wmx, (unsigned)__shfl_xor((int)wmx, m, 64));
        wmn = min(wmn, (unsigned)__shfl_xor((int)wmn, m, 64));
    }
    const int lane = t & 63, wid = t >> 6;
    if (lane == 0) { redmx[wid] = wmx; redmn[wid] = wmn; }
    __syncthreads();
    if (t == 0) {
        unsigned bx = redmx[0], bn = redmn[0];
        #pragma unroll
        for (int w = 1; w < 4; ++w) { bx = max(bx, redmx[w]); bn = min(bn, redmn[w]); }
        atomicMax(&mnmx[2*bb], bx);
        atomicMin(&mnmx[2*bb + 1], bn);
    }
}

// ---------------- Kernel 2a: full bitonic sort of 4096-chunks -------------
__global__ __launch_bounds__(1024) void k_sort_local(u64* __restrict__ keys) {
    __shared__ u64 sk[4096];
    const int base_g = blockIdx.x * 4096;
    const int tid = threadIdx.x;
    #pragma unroll
    for (int it = 0; it < 4; ++it) sk[tid + it*1024] = keys[base_g + tid + it*1024];
    __syncthreads();
    for (int k = 2; k <= 4096; k <<= 1) {
        for (int j = k >> 1; j > 0; j >>= 1) {
            int ii[2]; u64 a[2], c[2];
            #pragma unroll
            for (int it = 0; it < 2; ++it) {
                int q = tid + it*1024;
                int i = ((q & ~(j-1)) << 1) | (q & (j-1));
                ii[it] = i;
                a[it] = sk[i]; c[it] = sk[i | j];
            }
            #pragma unroll
            for (int it = 0; it < 2; ++it) {
                int gi = (base_g + ii[it]) & (NR - 1);
                bool dir = ((gi & k) == 0);
                if ((c[it] > a[it]) == dir) { sk[ii[it]] = c[it]; sk[ii[it] | j] = a[it]; }
            }
            __syncthreads();
        }
    }
    #pragma unroll
    for (int it = 0; it < 4; ++it) keys[base_g + tid + it*1024] = sk[tid + it*1024];
}

// ---------------- Kernel 2b: stage k=8192 with j=4096 folded into load ----
// Block owns 4096-chunk c (of 4 per batch). Partner chunk p = c^1 holds the
// j=4096 counterpart at the same local index. Selection per gpass semantics:
// halfdir=((g&8192)==0), low=((g&4096)==0) -> keep max iff halfdir==low.
__global__ __launch_bounds__(1024) void k_mtail_f(u64* __restrict__ keys) {
    __shared__ u64 sk[4096];
    const int blk = blockIdx.x;
    const int b = blk >> 2, c = blk & 3;
    const int tid = threadIdx.x;
    const u64* own  = keys + (size_t)b * NR + c * 4096;
    const u64* part = keys + (size_t)b * NR + (c ^ 1) * 4096;
    const bool halfdir = (c < 2);
    const bool keepmax = (halfdir == ((c & 1) == 0));

    #pragma unroll
    for (int it = 0; it < 4; ++it) {
        int i = tid + it*1024;
        u64 a = own[i], p = part[i];
        sk[i] = keepmax ? (a > p ? a : p) : (a > p ? p : a);
    }
    __syncthreads();
    for (int j = 2048; j >= 1; j >>= 1) {
        int ii[2]; u64 a[2], cc[2];
        #pragma unroll
        for (int it = 0; it < 2; ++it) {
            int q = tid + it*1024;
            int i = ((q & ~(j-1)) << 1) | (q & (j-1));
            ii[it] = i;
            a[it] = sk[i]; cc[it] = sk[i | j];
        }
        #pragma unroll
        for (int it = 0; it < 2; ++it) {
            if ((cc[it] > a[it]) == halfdir) { sk[ii[it]] = cc[it]; sk[ii[it] | j] = a[it]; }
        }
        __syncthreads();
    }
    u64* dst = keys + (size_t)b * NR + c * 4096;
    #pragma unroll
    for (int it = 0; it < 4; ++it) dst[tid + it*1024] = sk[tid + it*1024];
}

// ---------------- Kernel 3a: cross16-fold + final tail + scan + chunk hull
__global__ __launch_bounds__(1024) void k_hullA(
    u64* __restrict__ keys, const unsigned* __restrict__ mnmx,
    int* __restrict__ Hg, double* __restrict__ Svg,
    int* __restrict__ cntg, double* __restrict__ sumg)
{
    __shared__ __align__(16) char smem[32768 + 16384 + 128 + 1024 + 3*512];
    u64*    sk  = (u64*)smem;            // [4096] sort phase
    double* S   = (double*)smem;         // [4096] scan phase (overlay)
    int*    H   = (int*)(smem + 32768);  // [4096]
    double* Wt  = (double*)(smem + 32768 + 16384);          // [16]
    int*    cnt = (int*)(smem + 32768 + 16384 + 128);       // [256]
    int*    ti  = (int*)(smem + 32768 + 16384 + 128 + 1024);
    int*    tj  = (int*)(smem + 32768 + 16384 + 128 + 1024 + 512);
    int*    crA = (int*)(smem + 32768 + 16384 + 128 + 1024 + 1024);

    const int blk = blockIdx.x;
    const int b = blk >> 2, c = blk & 3;
    const int tid = threadIdx.x, lane = tid & 63, wid = tid >> 6;
    const u64* kbat = keys + (size_t)b * NR;
    u64* kg = keys + (size_t)b * NR + c * 4096;

    // ---- load with k=16384 phases j=8192,4096 folded (4-elem desc network)
    #pragma unroll
    for (int it = 0; it < 4; ++it) {
        int i = tid + it*1024;
        u64 e0 = kbat[i], e1 = kbat[i + 4096], e2 = kbat[i + 8192], e3 = kbat[i + 12288];
        u64 t;
        if (e2 > e0) { t = e0; e0 = e2; e2 = t; }   // j=8192
        if (e3 > e1) { t = e1; e1 = e3; e3 = t; }
        if (e1 > e0) { t = e0; e0 = e1; e1 = t; }   // j=4096
        if (e3 > e2) { t = e2; e2 = e3; e3 = t; }
        sk[i] = (c == 0) ? e0 : (c == 1) ? e1 : (c == 2) ? e2 : e3;
    }
    __syncthreads();

    // ---- final bitonic tail (k=16384, j<=2048, descending) ----
    for (int j = 2048; j >= 1; j >>= 1) {
        int ii[2]; u64 a[2], cc[2];
        #pragma unroll
        for (int it = 0; it < 2; ++it) {
            int q = tid + it*1024;
            int i = ((q & ~(j-1)) << 1) | (q & (j-1));
            ii[it] = i;
            a[it] = sk[i]; cc[it] = sk[i | j];
        }
        #pragma unroll
        for (int it = 0; it < 2; ++it) {
            if (cc[it] > a[it]) { sk[ii[it]] = cc[it]; sk[ii[it] | j] = a[it]; }
        }
        __syncthreads();
    }

    // ---- writeback sorted chunk; local f64 scan (4 elems/thread) ----
    const float mx = u2f(mnmx[2*b]);
    const float mn = u2f(mnmx[2*b + 1]);
    const float scale = 10000.0f / (mx - mn);
    const int gofs = c * 4096;
    const int b4 = tid * 4;

    u64 kv[4];
    #pragma unroll
    for (int r = 0; r < 4; ++r) kv[r] = sk[b4 + r];
    #pragma unroll
    for (int it = 0; it < 4; ++it) kg[tid + it*1024] = sk[tid + it*1024];

    double loc[4];
    double acc = 0.0;
    #pragma unroll
    for (int r = 0; r < 4; ++r) {
        int ig = gofs + b4 + r;
        float s_i = (u2f((unsigned)(kv[r] >> 32)) - mn) * scale;
        acc += (double)s_i - (double)(NR - ig);
        loc[r] = acc;
    }
    __syncthreads();     // ALL sk reads complete before S overlay writes

    double v = acc;
    #pragma unroll
    for (int d = 1; d < 64; d <<= 1) {
        double o = __shfl_up(v, d, 64);
        if (lane >= d) v += o;
    }
    if (lane == 63) Wt[wid] = v;
    __syncthreads();
    if (tid < 16) {
        double w = Wt[tid];
        #pragma unroll
        for (int d = 1; d < 16; d <<= 1) {
            double o = __shfl_up(w, d, 16);
            if ((tid & 15) >= d) w += o;
        }
        Wt[tid] = w;
    }
    __syncthreads();
    const double wbase = (wid == 0) ? 0.0 : Wt[wid - 1];
    const double excl = wbase + (v - acc);
    #pragma unroll
    for (int r = 0; r < 4; ++r) S[b4 + r] = excl + loc[r];
    __syncthreads();
    if (tid == 0) sumg[blk] = S[4095];

    #define SVA(k) ((k) == 0 ? 0.0 : S[(k)-1])

    // level-0: 16-point hulls on threads 0..255, stack top reg-cached
    if (tid < 256) {
        const int base16 = tid * 16;
        int out = 0;
        int k1 = 0, k2 = 0; double y1 = 0.0, y2 = 0.0;
        #pragma unroll 1
        for (int r = 0; r < 16; ++r) {
            int k = base16 + r;
            double yk = SVA(k);
            while (out >= 2) {
                double cr_ = (double)(k1 - k2)*(yk - y2) - (y1 - y2)*(double)(k - k2);
                if (cr_ >= 0.0) {
                    --out; k1 = k2; y1 = y2;
                    if (out >= 2) { k2 = H[base16 + out - 2]; y2 = SVA(k2); }
                } else break;
            }
            H[base16 + out] = k;
            k2 = k1; y2 = y1; k1 = k; y1 = yk;
            ++out;
        }
        cnt[tid] = out;
    }

    // 8 merge levels (256 -> 1)
    for (int lev = 0; lev < 8; ++lev) {
        __syncthreads();
        const int pairs = 128 >> lev;
        const int Wd = 16 << lev;
        if (tid < pairs) {
            const int lbase = tid * 2 * Wd;
            const int rbase = lbase + Wd;
            int cl = cnt[(2*tid) << lev];
            int cr = cnt[(2*tid+1) << lev];
            int i = cl - 1, j = 0;
            int kLi = H[lbase + i];            double yLi = SVA(kLi);
            int kLm = 0;                       double yLm = 0.0;
            if (i > 0) { kLm = H[lbase + i - 1]; yLm = SVA(kLm); }
            int kRj = H[rbase];                double yRj = SVA(kRj);
            int kRn = 0;                       double yRn = 0.0;
            if (cr > 1) { kRn = H[rbase + 1]; yRn = SVA(kRn); }
            bool moved = true;
            while (moved) {
                moved = false;
                while (i > 0) {
                    double cr_ = (double)(kLi - kLm)*(yRj - yLm)
                               - (yLi - yLm)*(double)(kRj - kLm);
                    if (cr_ >= 0.0) {
                        --i; kLi = kLm; yLi = yLm;
                        if (i > 0) { kLm = H[lbase + i - 1]; yLm = SVA(kLm); }
                        moved = true;
                    } else break;
                }
                while (j < cr - 1) {
                    double cr_ = (double)(kRj - kLi)*(yRn - yLi)
                               - (yRj - yLi)*(double)(kRn - kLi);
                    if (cr_ >= 0.0) {
                        ++j; kRj = kRn; yRj = yRn;
                        if (j < cr - 1) { kRn = H[rbase + j + 1]; yRn = SVA(kRn); }
                        moved = true;
                    } else break;
                }
            }
            ti[tid] = i; tj[tid] = j; crA[tid] = cr;
            cnt[(2*tid) << lev] = (i + 1) + (cr - j);
        }
        __syncthreads();
        const int tpp = 8 << lev;
        const int p = tid / tpp;
        const int q = tid % tpp;
        int vals[8];
        int len = 0, srcb = 0, dstb = 0;
        if (p < pairs) {
            const int lbase = p * 2 * Wd;
            const int rbase = lbase + Wd;
            const int i = ti[p], j = tj[p], cr = crA[p];
            len = cr - j;
            srcb = rbase + j;
            dstb = lbase + i + 1;
            #pragma unroll
            for (int t2 = 0; t2 < 8; ++t2) {
                int e2 = q + t2 * tpp;
                if (e2 < len) vals[t2] = H[srcb + e2];
            }
        }
        __syncthreads();
        if (p < pairs) {
            #pragma unroll
            for (int t2 = 0; t2 < 8; ++t2) {
                int e2 = q + t2 * tpp;
                if (e2 < len) H[dstb + e2] = vals[t2];
            }
        }
        __syncthreads();
    }

    // write chunk hull (global k, local f64 S at points)
    const int m = cnt[0];
    for (int p = tid; p < m; p += 1024) {
        int k = H[p];
        Hg[(size_t)blk * 4096 + p]  = k + gofs;
        Svg[(size_t)blk * 4096 + p] = SVA(k);
    }
    if (tid == 0) cntg[blk] = m;
    #undef SVA
}

// ---------------- Kernel 3b: merge 4 chunk hulls per batch + segments -----
__global__ __launch_bounds__(1024) void k_hullB(
    const double* __restrict__ sumg,
    int* __restrict__ Hg, double* __restrict__ Svg,
    const int* __restrict__ cntg,
    int* __restrict__ segk, float* __restrict__ segs, int* __restrict__ mseg)
{
    __shared__ int cnt[4];
    __shared__ int tiS[2], tjS[2], crS[2];
    __shared__ double beta[5];
    const int b = blockIdx.x;
    const int tid = threadIdx.x;
    int*    Hb = Hg  + (size_t)b * NR;
    double* Sb = Svg + (size_t)b * NR;

    if (tid < 4) cnt[tid] = cntg[4*b + tid];
    if (tid == 0) {
        double s = 0.0;
        #pragma unroll
        for (int c = 0; c < 4; ++c) { beta[c] = s; s += sumg[4*b + c]; }
        beta[4] = s;
    }
    __syncthreads();

    #pragma unroll 1
    for (int c = 0; c < 4; ++c) {
        const double bc = beta[c];
        for (int p = tid; p < cnt[c]; p += 1024) Sb[c*4096 + p] += bc;
    }
    __syncthreads();

    for (int lev = 0; lev < 2; ++lev) {
        const int pairs = 2 >> lev;
        const int Wd = 4096 << lev;
        if (tid < pairs) {
            const int lbase = tid * 2 * Wd;
            const int rbase = lbase + Wd;
            int cl = cnt[(2*tid) << lev];
            int cr = cnt[(2*tid+1) << lev];
            int i = cl - 1, j = 0;
            int kLi = Hb[lbase + i];            double yLi = Sb[lbase + i];
            int kLm = 0;                        double yLm = 0.0;
            if (i > 0) { kLm = Hb[lbase + i - 1]; yLm = Sb[lbase + i - 1]; }
            int kRj = Hb[rbase];                double yRj = Sb[rbase];
            int kRn = 0;                        double yRn = 0.0;
            if (cr > 1) { kRn = Hb[rbase + 1]; yRn = Sb[rbase + 1]; }
            bool moved = true;
            while (moved) {
                moved = false;
                while (i > 0) {
                    double cr_ = (double)(kLi - kLm)*(yRj - yLm)
                               - (yLi - yLm)*(double)(kRj - kLm);
                    if (cr_ >= 0.0) {
                        --i; kLi = kLm; yLi = yLm;
                        if (i > 0) { kLm = Hb[lbase + i - 1]; yLm = Sb[lbase + i - 1]; }
                        moved = true;
                    } else break;
                }
                while (j < cr - 1) {
                    double cr_ = (double)(kRj - kLi)*(yRn - yLi)
                               - (yRj - yLi)*(double)(kRn - kLi);
                    if (cr_ >= 0.0) {
                        ++j; kRj = kRn; yRj = yRn;
                        if (j < cr - 1) { kRn = Hb[rbase + j + 1]; yRn = Sb[rbase + j + 1]; }
                        moved = true;
                    } else break;
                }
            }
            tiS[tid] = i; tjS[tid] = j; crS[tid] = cr;
            cnt[(2*tid) << lev] = (i + 1) + (cr - j);
        }
        __syncthreads();
        const int tpp = (lev == 0) ? 512 : 1024;
        const int p = tid / tpp;
        const int q = tid % tpp;
        int hv[8]; double sv[8];
        int len = 0, srcb = 0, dstb = 0;
        if (p < pairs) {
            const int lbase = p * 2 * Wd;
            const int rbase = lbase + Wd;
            const int i = tiS[p], j = tjS[p], cr = crS[p];
            len = cr - j;
            srcb = rbase + j;
            dstb = lbase + i + 1;
            #pragma unroll
            for (int t2 = 0; t2 < 8; ++t2) {
                int e2 = q + t2 * tpp;
                if (e2 < len) { hv[t2] = Hb[srcb + e2]; sv[t2] = Sb[srcb + e2]; }
            }
        }
        __syncthreads();
        if (p < pairs) {
            #pragma unroll
            for (int t2 = 0; t2 < 8; ++t2) {
                int e2 = q + t2 * tpp;
                if (e2 < len) { Hb[dstb + e2] = hv[t2]; Sb[dstb + e2] = sv[t2]; }
            }
        }
        __syncthreads();
    }

    if (tid == 0) {
        const double total = beta[4];
        int out = cnt[0];
        while (out >= 2) {
            int ka = Hb[out - 2], kb2 = Hb[out - 1];
            double ya = Sb[out - 2], yb = Sb[out - 1];
            double cr_ = (double)(kb2 - ka)*(total - ya) - (yb - ya)*(double)(NR - ka);
            if (cr_ >= 0.0) --out;
            else break;
        }
        Hb[out] = NR; Sb[out] = total;
        cnt[0] = out + 1;
    }
    __syncthreads();

    const int m = cnt[0];
    for (int p = tid; p < m - 1; p += 1024) {
        int ka = Hb[p], kb2 = Hb[p + 1];
        segk[(size_t)b * SEGP + p] = ka;
        segs[(size_t)b * SEGP + p] = (float)((Sb[p + 1] - Sb[p]) / (double)(kb2 - ka));
    }
    if (tid == 0) mseg[b] = m;
}

// ---------------- Kernel 3c: outputs (full width) -------------------------
__global__ __launch_bounds__(256) void k_out(
    const u64* __restrict__ keys, const unsigned* __restrict__ mnmx,
    const int* __restrict__ capp,
    const int* __restrict__ segk, const float* __restrict__ segs,
    const int* __restrict__ mseg,
    float* __restrict__ out_soft, float* __restrict__ out_bins)
{
    const int gb = blockIdx.x;           // 512 blocks: 16 per batch
    const int b = gb >> 4, part = gb & 15;
    const int tid = threadIdx.x;
    const int m = mseg[b];
    const float mx = u2f(mnmx[2*b]);
    const float mn = u2f(mnmx[2*b + 1]);
    const float scale = 10000.0f / (mx - mn);
    const int cap = capp[0];
    const int base = part * 1024;
    const int* __restrict__ sk2 = segk + (size_t)b * SEGP;
    const float* __restrict__ ss2 = segs + (size_t)b * SEGP;

    int lo[4], hi[4];
    #pragma unroll
    for (int r = 0; r < 4; ++r) { lo[r] = 0; hi[r] = m - 1; }
    for (int step = 0; step < 14; ++step) {
        int hm[4];
        #pragma unroll
        for (int r = 0; r < 4; ++r)
            if (hi[r] - lo[r] > 1) hm[r] = sk2[(lo[r] + hi[r]) >> 1];
        #pragma unroll
        for (int r = 0; r < 4; ++r) {
            if (hi[r] - lo[r] > 1) {
                int mid = (lo[r] + hi[r]) >> 1;
                int i = base + tid + (r << 8);
                if (hm[r] <= i) lo[r] = mid; else hi[r] = mid;
            }
        }
    }
    #pragma unroll
    for (int r = 0; r < 4; ++r) {
        const int i = base + tid + (r << 8);
        u64 key = keys[(size_t)b * NR + i];
        float s_i = (u2f((unsigned)(key >> 32)) - mn) * scale;
        float primal = s_i - ss2[lo[r]];
        int idx = (int)(key & 0xffffffffu);
        out_soft[(size_t)b * NR + idx] = primal;
        int rank = (NR - 1) - i;
        out_bins[(size_t)b * NR + idx] = (float)(rank / cap + 1);
    }
}

extern "C" void kernel_launch(void* const* d_in, const int* in_sizes, int n_in,
                              void* d_out, int out_size, void* d_ws, size_t ws_size,
                              hipStream_t stream)
{
    const float* table = (const float*)d_in[0];
    const float* ln1_g = (const float*)d_in[1];
    const float* ln1_b = (const float*)d_in[2];
    const float* W1    = (const float*)d_in[3];
    const float* b1    = (const float*)d_in[4];
    const float* ln2_g = (const float*)d_in[5];
    const float* ln2_b = (const float*)d_in[6];
    const float* W2    = (const float*)d_in[7];
    const float* b2    = (const float*)d_in[8];
    const int*   cap   = (const int*)d_in[9];

    u64*      keys   = (u64*)d_ws;                    // TOT u64   (4 MiB)
    double*   Svg    = (double*)(keys + TOT);         // TOT f64   (4 MiB)
    double*   sumg   = Svg + TOT;                     // 128 f64
    float*    W1g    = (float*)(sumg + 128);          // 4096 f32
    float*    consts = W1g + NF*NH;                   // 64 f32
    unsigned* mnmx   = (unsigned*)(consts + 64);      // 64 u32
    int*      Hg     = (int*)(mnmx + 64);             // TOT i32   (2 MiB)
    int*      cntg   = Hg + TOT;                      // 128 i32
    int*      segk   = cntg + 128;                    // NB*SEGP i32
    float*    segs   = (float*)(segk + NB*SEGP);      // NB*SEGP f32
    int*      mseg   = (int*)(segs + NB*SEGP);        // NB i32

    float* out_soft = (float*)d_out;
    float* out_bins = ((float*)d_out) + TOT;

    k_prep<<<1, 256, 0, stream>>>(ln1_g, ln1_b, W1, b1, ln2_g, ln2_b, W2, b2,
                                  W1g, consts, mnmx);
    k_scores<<<TOT/RPB, 256, 0, stream>>>(table, W1g, consts, keys, mnmx);

    k_sort_local<<<TOT/4096, 1024, 0, stream>>>(keys);   // k <= 4096
    k_mtail_f<<<TOT/4096, 1024, 0, stream>>>(keys);      // k = 8192 (j=4096 folded)
    k_hullA<<<NB*4, 1024, 0, stream>>>(keys, mnmx, Hg, Svg, cntg, sumg);
    k_hullB<<<NB, 1024, 0, stream>>>(sumg, Hg, Svg, cntg, segk, segs, mseg);
    k_out<<<NB*16, 256, 0, stream>>>(keys, mnmx, cap, segk, segs, mseg,
                                     out_soft, out_bins);
}